// Round 5
// baseline (98.207 us; speedup 1.0000x reference)
//
#include <hip/hip_runtime.h>
#include <hip/hip_bf16.h>
#include <hip/hip_cooperative_groups.h>

namespace cg = cooperative_groups;

// Outer_14173392076867 — single cooperative kernel, MI355X gfx950.
// Phase 0: fc1_w f32->bf16 (k-major [64][32768]) into ws (w1b)
// Phase A: per-(ih,h,ng16) dX -> att tiles in LDS (16 n per block)
// [grid sync: cvt visible chip-wide]
// Phase B: fc1 partial GEMM, w1b streamed from same-XCD L2
// [grid sync: partials visible]
// Phase C: one wave per n: reduce 16 partials + bias + silu + fc2 -> out[256]

typedef __attribute__((ext_vector_type(8))) short short8;
typedef __attribute__((ext_vector_type(4))) float f32x4;
typedef __attribute__((ext_vector_type(4))) unsigned short u16x4;

#define PADW 72      // LDS row pad (ushorts): 144B rows, 16B aligned, 2-way banks
#define PADM 2056    // att row: 2048 + 8 ushorts -> 4112B rows
#define KTOT 32768L

__device__ __forceinline__ unsigned short f2b(float x) {
  union { float f; unsigned int u; } v; v.f = x;
  return (unsigned short)((v.u + 0x7FFFu + ((v.u >> 16) & 1u)) >> 16);
}

// packed f32x2 -> bf16x2 (RNE), single v_cvt_pk_bf16_f32
__device__ __forceinline__ unsigned int pk_bf16(float lo, float hi) {
  unsigned int r;
  asm("v_cvt_pk_bf16_f32 %0, %1, %2" : "=v"(r) : "v"(lo), "v"(hi));
  return r;
}

__global__ __launch_bounds__(512, 1)
void k_all(const float* __restrict__ X, const float* __restrict__ Wl_g,
           const float* __restrict__ Wr_g, const float* __restrict__ fc1w,
           const float* __restrict__ fc1b, const float* __restrict__ fc2w,
           const float* __restrict__ fc2b,
           unsigned short* __restrict__ w1b, float* __restrict__ partial,
           float* __restrict__ out) {
  __shared__ float xs[16][3][64];                              // 12288 B
  __shared__ __align__(16) union {
    struct {
      unsigned short wl[64][PADW];                             //  9216 B
      unsigned short wr[64][PADW];                             //  9216 B
      unsigned short dxs[2][3][32][PADW];                      // 27648 B
    } a;
    float red[8][16][64];                                      // 32768 B
  } u;                                                         // 46080 B
  __shared__ __align__(16) unsigned short att_s[16][PADM];     // 65792 B => 124160 B

  const int blk  = blockIdx.x;
  const int ih   = blk & 1;
  const int h    = (blk >> 1) & 7;
  const int ng   = blk >> 4;
  const int tid  = threadIdx.x;
  const int lane = tid & 63;
  const int w    = tid >> 6;
  const int c0   = lane & 15;
  const int ks   = lane >> 4;
  const int iw   = (w >> 1) & 1;
  const int dw   = w & 1;
  const int qsub = w >> 2;

  // ---- Phase 0: cvt fc1_w slice (8192 f32 per block, 16 per thread)
  {
    const int base = (blk * 512 + tid) * 16;
#pragma unroll
    for (int r = 0; r < 4; ++r) {
      f32x4 v = *(const f32x4*)(fc1w + base + r * 4);
      u16x4 o;
#pragma unroll
      for (int e = 0; e < 4; ++e) o[e] = f2b(v[e]);
      *(u16x4*)(w1b + base + r * 4) = o;
    }
  }

  // ---- W slices (per h): coalesced f32 read, transposed bf16 store [d][j]
  const float* wlg = Wl_g + h * 4096;
  const float* wrg = Wr_g + h * 4096;
#pragma unroll
  for (int r = 0; r < 8; ++r) {
    int e = tid + r * 512;
    int j = e >> 6, d = e & 63;
    u.a.wl[d][j] = f2b(wlg[e]);
    u.a.wr[d][j] = f2b(wrg[e]);
  }
  // ---- X for 16 n: [q][t][i] (3072 floats, coalesced)
  {
    const long xbase = ((long)(ng * 16) * 8 + h) * 192;
#pragma unroll
    for (int r = 0; r < 6; ++r) {
      int e = tid + r * 512;
      int q = e / 192;
      int rem = e - q * 192;
      int i = rem / 3;
      int t = rem - i * 3;
      xs[q][t][i] = X[xbase + (long)q * 1536 + rem];
    }
  }
  __syncthreads();

  // ---- B fragments for the att GEMM (this wave's d-half), t-invariant
  short8 bl[2][2], br[2][2];
#pragma unroll
  for (int cb = 0; cb < 2; ++cb)
#pragma unroll
    for (int kb = 0; kb < 2; ++kb) {
      const int d = c0 + 16 * cb + 32 * dw;
      const int j0 = ks * 8 + 32 * kb;
      bl[cb][kb] = *(const short8*)&u.a.wl[d][j0];
      br[cb][kb] = *(const short8*)&u.a.wr[d][j0];
    }

  const int dq  = tid >> 8;          // dX sub-buffer this thread fills (0/1)
  const int il  = (tid >> 3) & 31;   // dX row (local, 0..31)
  const int jb  = (tid & 7) << 3;    // 8-col chunk

  for (int it = 0; it < 8; ++it) {
    const int qd = it * 2 + dq;
    if (it) __syncthreads();
    // dX[i = ih*32+il][j], 3 t's, 8 j's per thread
#pragma unroll
    for (int t = 0; t < 3; ++t) {
      const float xi = xs[qd][t][ih * 32 + il];
#pragma unroll
      for (int jj = 0; jj < 8; jj += 2) {
        float d0 = xi - xs[qd][t][jb + jj];
        float d1 = xi - xs[qd][t][jb + jj + 1];
        float s0 = d0 * d0 + 1e-5f;
        float s1 = d1 * d1 + 1e-5f;
        float i0 = __builtin_amdgcn_rsqf(s0);
        float i1 = __builtin_amdgcn_rsqf(s1);
        float e0 = __builtin_amdgcn_exp2f(-1.44269504f * (s0 * i0));
        float e1 = __builtin_amdgcn_exp2f(-1.44269504f * (s1 * i1));
        *(unsigned int*)&u.a.dxs[dq][t][il][jb + jj] =
            pk_bf16(d0 * i0 * e0, d1 * i1 * e1);
      }
    }
    __syncthreads();

    // att tile for q = it*2 + qsub: wave computes [16 i x 32 d], K=64 over j
    const int q = it * 2 + qsub;
    f32x4 acc[2];
#pragma unroll
    for (int cb = 0; cb < 2; ++cb) {
      acc[cb][0] = 0.f; acc[cb][1] = 0.f; acc[cb][2] = 0.f; acc[cb][3] = 0.f;
    }
#pragma unroll
    for (int t = 0; t < 3; ++t) {
      short8 a0 = *(const short8*)&u.a.dxs[qsub][t][iw * 16 + c0][ks * 8];
      short8 a1 = *(const short8*)&u.a.dxs[qsub][t][iw * 16 + c0][ks * 8 + 32];
#pragma unroll
      for (int cb = 0; cb < 2; ++cb) {
        f32x4 xl; xl[0]=0.f; xl[1]=0.f; xl[2]=0.f; xl[3]=0.f;
        f32x4 xr; xr[0]=0.f; xr[1]=0.f; xr[2]=0.f; xr[3]=0.f;
        xl = __builtin_amdgcn_mfma_f32_16x16x32_bf16(a0, bl[cb][0], xl, 0, 0, 0);
        xl = __builtin_amdgcn_mfma_f32_16x16x32_bf16(a1, bl[cb][1], xl, 0, 0, 0);
        xr = __builtin_amdgcn_mfma_f32_16x16x32_bf16(a0, br[cb][0], xr, 0, 0, 0);
        xr = __builtin_amdgcn_mfma_f32_16x16x32_bf16(a1, br[cb][1], xr, 0, 0, 0);
        acc[cb] += xl * xr;
      }
    }
#pragma unroll
    for (int cb = 0; cb < 2; ++cb)
#pragma unroll
      for (int r = 0; r < 4; ++r) {
        int ro = iw * 16 + ks * 4 + r;
        int d = c0 + 16 * cb + 32 * dw;
        att_s[q][ro * 64 + d] = f2b(acc[cb][r]);
      }
  }
  __syncthreads();

  // ---- grid sync #1: all cvt (phase 0) writes visible before w1b reads
  cg::this_grid().sync();

  // ---- Phase B: fc1 partial, C[16n x 64k], wave w owns m-chunk 256
  f32x4 facc[4];
#pragma unroll
  for (int cb = 0; cb < 4; ++cb) {
    facc[cb][0] = 0.f; facc[cb][1] = 0.f; facc[cb][2] = 0.f; facc[cb][3] = 0.f;
  }
  const unsigned short* bp =
      w1b + (long)c0 * KTOT + h * 4096 + ih * 2048 + w * 256 + ks * 8;
  const unsigned short* ap = &att_s[0][0] + c0 * PADM + w * 256 + ks * 8;
#pragma unroll
  for (int s = 0; s < 8; ++s) {
    short8 a = *(const short8*)(ap + s * 32);
#pragma unroll
    for (int cb = 0; cb < 4; ++cb) {
      short8 b = *(const short8*)(bp + (long)cb * 16 * KTOT + s * 32);
      facc[cb] = __builtin_amdgcn_mfma_f32_16x16x32_bf16(a, b, facc[cb], 0, 0, 0);
    }
  }
  __syncthreads();                   // att_s reads done; u.red reuse
#pragma unroll
  for (int cb = 0; cb < 4; ++cb)
#pragma unroll
    for (int r = 0; r < 4; ++r)
      u.red[w][ks * 4 + r][c0 + 16 * cb] = facc[cb][r];
  __syncthreads();
#pragma unroll
  for (int rep = 0; rep < 2; ++rep) {
    int e = tid + rep * 512;
    int nl = e >> 6, k = e & 63;
    float s = 0.f;
#pragma unroll
    for (int ww = 0; ww < 8; ++ww) s += u.red[ww][nl][k];
    partial[(((long)h * 2 + ih) * 256 + ng * 16 + nl) * 64 + k] = s;
  }

  // ---- grid sync #2: partials visible chip-wide
  cg::this_grid().sync();

  // ---- Phase C: one wave per n (block blk handles n = blk)
  if (tid < 64) {
    const int n = blk;
    const int k = tid;
    float s = fc1b[k];
#pragma unroll
    for (int sp = 0; sp < 16; ++sp)
      s += partial[((long)sp * 256 + n) * 64 + k];
    float g = s / (1.f + __expf(-s));   // silu
    float v = g * fc2w[k];
#pragma unroll
    for (int off = 32; off > 0; off >>= 1)
      v += __shfl_xor(v, off, 64);
    if (k == 0) out[n] = v + fc2b[0];
  }
}

extern "C" void kernel_launch(void* const* d_in, const int* in_sizes, int n_in,
                              void* d_out, int out_size, void* d_ws, size_t ws_size,
                              hipStream_t stream) {
  const float* X    = (const float*)d_in[0];
  const float* Wl   = (const float*)d_in[1];
  const float* Wr   = (const float*)d_in[2];
  const float* fc1w = (const float*)d_in[3];
  const float* fc1b = (const float*)d_in[4];
  const float* fc2w = (const float*)d_in[5];
  const float* fc2b = (const float*)d_in[6];
  float* out = (float*)d_out;

  char* ws = (char*)d_ws;
  unsigned short* w1b     = (unsigned short*)(ws);             // 4,194,304 B
  float*          partial = (float*)(ws + 4194304);            // 1,048,576 B

  void* args[] = {(void*)&X, (void*)&Wl, (void*)&Wr, (void*)&fc1w,
                  (void*)&fc1b, (void*)&fc2w, (void*)&fc2b,
                  (void*)&w1b, (void*)&partial, (void*)&out};
  hipLaunchCooperativeKernel((void*)k_all, dim3(256), dim3(512), args, 0, stream);
}

// Round 8
// 38.524 us; speedup vs baseline: 2.5492x; 2.5492x over previous
//
#include <hip/hip_runtime.h>
#include <hip/hip_bf16.h>

// Outer_14173392076867 — 2-kernel pipeline v7, MI355X gfx950.
// K1: fused per-(ih,h,ng16): dX -> att (LDS, 16 n) -> fc1 partial GEMM,
//     fc1_w streamed as f32 from same-XCD L2, converted in-register via the
//     proven f2b bit-twiddle (v6's v_cvt_pk_bf16_f32 pack miscompiled here).
// K2: reduce 16 partials + bias + silu + fc2 -> out[256]

typedef __attribute__((ext_vector_type(8))) short short8;
typedef __attribute__((ext_vector_type(4))) float f32x4;

#define PADW 72      // LDS row pad (ushorts): 144B rows, 16B aligned, 2-way banks
#define PADM 2056    // att row: 2048 + 8 ushorts -> 4112B rows
#define KTOT 32768L

__device__ __forceinline__ unsigned short f2b(float x) {
  union { float f; unsigned int u; } v; v.f = x;
  return (unsigned short)((v.u + 0x7FFFu + ((v.u >> 16) & 1u)) >> 16);
}

// packed f32x2 -> bf16x2 (RNE), single v_cvt_pk_bf16_f32 (proven in dX path)
__device__ __forceinline__ unsigned int pk_bf16(float a, float b) {
  unsigned int r;
  asm("v_cvt_pk_bf16_f32 %0, %1, %2" : "=v"(r) : "v"(a), "v"(b));
  return r;
}

// ---------------- K1: fused dX -> att (LDS) -> fc1 partial ----------------
// grid = 256: ih = blk&1, h = (blk>>1)&7, ng = blk>>4 (16 n's per block).
// block = 512 (8 waves). Phase A: 8 double-q iterations (2 q in flight).
// Phase B: wave w owns m-chunk of 256; 16-row A-frags.
__global__ __launch_bounds__(512, 1)
void k_fused(const float* __restrict__ X, const float* __restrict__ Wl_g,
             const float* __restrict__ Wr_g,
             const float* __restrict__ fc1w,
             float* __restrict__ partial) {
  __shared__ float xs[16][3][64];                              // 12288 B
  __shared__ __align__(16) union {
    struct {
      unsigned short wl[64][PADW];                             //  9216 B
      unsigned short wr[64][PADW];                             //  9216 B
      unsigned short dxs[2][3][32][PADW];                      // 27648 B
    } a;
    float red[8][16][64];                                      // 32768 B
  } u;                                                         // 46080 B
  __shared__ __align__(16) unsigned short att_s[16][PADM];     // 65792 B => 124160 B

  const int blk  = blockIdx.x;
  const int ih   = blk & 1;
  const int h    = (blk >> 1) & 7;
  const int ng   = blk >> 4;
  const int tid  = threadIdx.x;
  const int lane = tid & 63;
  const int w    = tid >> 6;
  const int c0   = lane & 15;
  const int ks   = lane >> 4;
  const int iw   = (w >> 1) & 1;
  const int dw   = w & 1;
  const int qsub = w >> 2;

  // ---- W slices (per h): coalesced f32 read, transposed bf16 store [d][j]
  const float* wlg = Wl_g + h * 4096;
  const float* wrg = Wr_g + h * 4096;
#pragma unroll
  for (int r = 0; r < 8; ++r) {
    int e = tid + r * 512;
    int j = e >> 6, d = e & 63;
    u.a.wl[d][j] = f2b(wlg[e]);
    u.a.wr[d][j] = f2b(wrg[e]);
  }
  // ---- X for 16 n: [q][t][i] (3072 floats, coalesced)
  {
    const long xbase = ((long)(ng * 16) * 8 + h) * 192;
#pragma unroll
    for (int r = 0; r < 6; ++r) {
      int e = tid + r * 512;
      int q = e / 192;
      int rem = e - q * 192;
      int i = rem / 3;
      int t = rem - i * 3;
      xs[q][t][i] = X[xbase + (long)q * 1536 + rem];
    }
  }
  __syncthreads();

  // ---- B fragments for the att GEMM (this wave's d-half), t-invariant
  short8 bl[2][2], br[2][2];
#pragma unroll
  for (int cb = 0; cb < 2; ++cb)
#pragma unroll
    for (int kb = 0; kb < 2; ++kb) {
      const int d = c0 + 16 * cb + 32 * dw;
      const int j0 = ks * 8 + 32 * kb;
      bl[cb][kb] = *(const short8*)&u.a.wl[d][j0];
      br[cb][kb] = *(const short8*)&u.a.wr[d][j0];
    }

  const int dq  = tid >> 8;          // dX sub-buffer this thread fills (0/1)
  const int il  = (tid >> 3) & 31;   // dX row (local, 0..31)
  const int jb  = (tid & 7) << 3;    // 8-col chunk

  for (int it = 0; it < 8; ++it) {
    const int qd = it * 2 + dq;
    if (it) __syncthreads();
    // dX[i = ih*32+il][j], 3 t's, 8 j's per thread
#pragma unroll
    for (int t = 0; t < 3; ++t) {
      const float xi = xs[qd][t][ih * 32 + il];
#pragma unroll
      for (int jj = 0; jj < 8; jj += 2) {
        float d0 = xi - xs[qd][t][jb + jj];
        float d1 = xi - xs[qd][t][jb + jj + 1];
        float s0 = d0 * d0 + 1e-5f;
        float s1 = d1 * d1 + 1e-5f;
        float i0 = __builtin_amdgcn_rsqf(s0);
        float i1 = __builtin_amdgcn_rsqf(s1);
        float e0 = __builtin_amdgcn_exp2f(-1.44269504f * (s0 * i0));
        float e1 = __builtin_amdgcn_exp2f(-1.44269504f * (s1 * i1));
        *(unsigned int*)&u.a.dxs[dq][t][il][jb + jj] =
            pk_bf16(d0 * i0 * e0, d1 * i1 * e1);
      }
    }
    __syncthreads();

    // att tile for q = it*2 + qsub: wave computes [16 i x 32 d], K=64 over j
    const int q = it * 2 + qsub;
    f32x4 acc[2];
#pragma unroll
    for (int cb = 0; cb < 2; ++cb) {
      acc[cb][0] = 0.f; acc[cb][1] = 0.f; acc[cb][2] = 0.f; acc[cb][3] = 0.f;
    }
#pragma unroll
    for (int t = 0; t < 3; ++t) {
      short8 a0 = *(const short8*)&u.a.dxs[qsub][t][iw * 16 + c0][ks * 8];
      short8 a1 = *(const short8*)&u.a.dxs[qsub][t][iw * 16 + c0][ks * 8 + 32];
#pragma unroll
      for (int cb = 0; cb < 2; ++cb) {
        f32x4 xl; xl[0]=0.f; xl[1]=0.f; xl[2]=0.f; xl[3]=0.f;
        f32x4 xr; xr[0]=0.f; xr[1]=0.f; xr[2]=0.f; xr[3]=0.f;
        xl = __builtin_amdgcn_mfma_f32_16x16x32_bf16(a0, bl[cb][0], xl, 0, 0, 0);
        xl = __builtin_amdgcn_mfma_f32_16x16x32_bf16(a1, bl[cb][1], xl, 0, 0, 0);
        xr = __builtin_amdgcn_mfma_f32_16x16x32_bf16(a0, br[cb][0], xr, 0, 0, 0);
        xr = __builtin_amdgcn_mfma_f32_16x16x32_bf16(a1, br[cb][1], xr, 0, 0, 0);
        acc[cb] += xl * xr;
      }
    }
#pragma unroll
    for (int cb = 0; cb < 2; ++cb)
#pragma unroll
      for (int r = 0; r < 4; ++r) {
        int ro = iw * 16 + ks * 4 + r;
        int d = c0 + 16 * cb + 32 * dw;
        att_s[q][ro * 64 + d] = f2b(acc[cb][r]);
      }
  }
  __syncthreads();

  // ---- Phase B: fc1 partial, C[16n x 64k], wave w owns m-chunk 256.
  // B-frags streamed from fc1w (f32), converted with f2b (bit-identical to
  // the R4 pre-converted-w1b path).
  f32x4 facc[4];
#pragma unroll
  for (int cb = 0; cb < 4; ++cb) {
    facc[cb][0] = 0.f; facc[cb][1] = 0.f; facc[cb][2] = 0.f; facc[cb][3] = 0.f;
  }
  const float* bpf =
      fc1w + (long)c0 * KTOT + h * 4096 + ih * 2048 + w * 256 + ks * 8;
  const unsigned short* ap = &att_s[0][0] + c0 * PADM + w * 256 + ks * 8;
#pragma unroll
  for (int s = 0; s < 8; ++s) {
    short8 a = *(const short8*)(ap + s * 32);
#pragma unroll
    for (int cb = 0; cb < 4; ++cb) {
      const float* src = bpf + (long)cb * 16 * KTOT + s * 32;
      f32x4 v0 = *(const f32x4*)(src);
      f32x4 v1 = *(const f32x4*)(src + 4);
      union { unsigned short us[8]; short8 s8; } pw;
      pw.us[0] = f2b(v0[0]);
      pw.us[1] = f2b(v0[1]);
      pw.us[2] = f2b(v0[2]);
      pw.us[3] = f2b(v0[3]);
      pw.us[4] = f2b(v1[0]);
      pw.us[5] = f2b(v1[1]);
      pw.us[6] = f2b(v1[2]);
      pw.us[7] = f2b(v1[3]);
      facc[cb] = __builtin_amdgcn_mfma_f32_16x16x32_bf16(a, pw.s8, facc[cb], 0, 0, 0);
    }
  }
  __syncthreads();                   // att_s reads done; u.red reuse
#pragma unroll
  for (int cb = 0; cb < 4; ++cb)
#pragma unroll
    for (int r = 0; r < 4; ++r)
      u.red[w][ks * 4 + r][c0 + 16 * cb] = facc[cb][r];
  __syncthreads();
#pragma unroll
  for (int rep = 0; rep < 2; ++rep) {
    int e = tid + rep * 512;
    int nl = e >> 6, k = e & 63;
    float s = 0.f;
#pragma unroll
    for (int ww = 0; ww < 8; ++ww) s += u.red[ww][nl][k];
    partial[(((long)h * 2 + ih) * 256 + ng * 16 + nl) * 64 + k] = s;
  }
}

// ---------------- K2: reduce 16 partials + bias + silu + fc2 ----------------
__global__ __launch_bounds__(256)
void k_fc2(const float* __restrict__ partial, const float* __restrict__ fc1_b,
           const float* __restrict__ fc2_w, const float* __restrict__ fc2_b,
           float* __restrict__ out) {
  const int tid = threadIdx.x;
  const int n = blockIdx.x * 4 + (tid >> 6);
  const int k = tid & 63;
  float s = fc1_b[k];
#pragma unroll
  for (int sp = 0; sp < 16; ++sp)
    s += partial[((long)sp * 256 + n) * 64 + k];
  float g = s / (1.f + __expf(-s));   // silu
  float v = g * fc2_w[k];
#pragma unroll
  for (int off = 32; off > 0; off >>= 1)
    v += __shfl_xor(v, off, 64);
  if (k == 0) out[n] = v + fc2_b[0];
}

extern "C" void kernel_launch(void* const* d_in, const int* in_sizes, int n_in,
                              void* d_out, int out_size, void* d_ws, size_t ws_size,
                              hipStream_t stream) {
  const float* X    = (const float*)d_in[0];
  const float* Wl   = (const float*)d_in[1];
  const float* Wr   = (const float*)d_in[2];
  const float* fc1w = (const float*)d_in[3];
  const float* fc1b = (const float*)d_in[4];
  const float* fc2w = (const float*)d_in[5];
  const float* fc2b = (const float*)d_in[6];
  float* out = (float*)d_out;

  float* partial = (float*)d_ws;                               // 1,048,576 B

  hipLaunchKernelGGL(k_fused, dim3(256), dim3(512), 0, stream, X, Wl, Wr, fc1w, partial);
  hipLaunchKernelGGL(k_fc2,   dim3(64), dim3(256), 0, stream, partial, fc1b, fc2w, fc2b, out);
}